// Round 5
// baseline (435.638 us; speedup 1.0000x reference)
//
#include <hip/hip_runtime.h>
#include <cstdint>

#define NSTEP 1000
#define NELEM 45056          // 16 * 2816  (n*s = 16 slices of 64x44)
#define HW    2816           // 64 * 44
#define EPB   64             // elements per block == consumer wave width
#define PW    8              // producer waves per block
#define BLK   ((PW + 1) * 64)// 576 threads: 8 producer waves + 1 consumer wave
#define RING  64             // LDS ring slots (power of 2)

// ---------- compile-time fp64 DDIM schedule (bit-exact vs np.linspace+cumprod) ----------
struct AlphTab { float a[NSTEP + 1]; };

constexpr AlphTab make_alph() {
    AlphTab t{};
    t.a[0] = 1.0f;
    double alph = 1.0;
    const double start = 1e-4, stop = 0.02;
    const double step = (stop - start) / 999.0;
    for (int i = 0; i < NSTEP; ++i) {
        double beta = (i == NSTEP - 1) ? stop : ((double)i * step + start);
        alph *= (1.0 - beta);
        t.a[i + 1] = (float)alph;
    }
    return t;
}
constexpr AlphTab ALPH = make_alph();

// ---------- Threefry-2x32-20 (partitionable-mode usage: ctr=(0,j), out = x0^x1) ----------
__device__ __forceinline__ void tf20(uint32_t K0, uint32_t K1, uint32_t K2,
                                     uint32_t& x0, uint32_t& x1) {
    x0 += K0; x1 += K1;
#define TFR(r) { x0 += x1; x1 = ((x1 << r) | (x1 >> (32 - r))); x1 ^= x0; }
    TFR(13) TFR(15) TFR(26) TFR(6)
    x0 += K1; x1 += K2 + 1u;
    TFR(17) TFR(29) TFR(16) TFR(24)
    x0 += K2; x1 += K0 + 2u;
    TFR(13) TFR(15) TFR(26) TFR(6)
    x0 += K0; x1 += K1 + 3u;
    TFR(17) TFR(29) TFR(16) TFR(24)
    x0 += K1; x1 += K2 + 4u;
    TFR(13) TFR(15) TFR(26) TFR(6)
    x0 += K2; x1 += K0 + 5u;
#undef TFR
}

// bits -> erfinv(u). Dual-poly, single select; wave-uniform skip of the far
// branch (P(any of 64 lanes far) ~ 19%). Bit-identical to the reference poly.
__device__ __forceinline__ float bits_to_erfinv(uint32_t bits) {
    const float f2 = __uint_as_float((bits >> 9) | 0x3F800000u) - 1.0f;
    const float u  = f2 * 2.0f - 0.99999994f;
    const float t1 = (1.0f - u) * (1.0f + u);
    const float w  = __log2f(t1) * -0.6931472f;
    const bool  lt = w < 5.0f;

    const float wwn = w - 2.5f;
    float pn =           2.81022636e-08f;
    pn = fmaf(pn, wwn,   3.43273939e-07f);
    pn = fmaf(pn, wwn,  -3.5233877e-06f);
    pn = fmaf(pn, wwn,  -4.39150654e-06f);
    pn = fmaf(pn, wwn,   0.00021858087f);
    pn = fmaf(pn, wwn,  -0.00125372503f);
    pn = fmaf(pn, wwn,  -0.00417768164f);
    pn = fmaf(pn, wwn,   0.246640727f);
    pn = fmaf(pn, wwn,   1.50140941f);

    float p = pn;
    if (__any(!lt)) {                                 // wave-uniform branch
        const float sw  = __builtin_amdgcn_sqrtf(w);  // w >= 0 always
        const float wwf = sw - 3.0f;
        float pf =           -0.000200214257f;
        pf = fmaf(pf, wwf,    0.000100950558f);
        pf = fmaf(pf, wwf,    0.00134934322f);
        pf = fmaf(pf, wwf,   -0.00367342844f);
        pf = fmaf(pf, wwf,    0.00573950773f);
        pf = fmaf(pf, wwf,   -0.0076224613f);
        pf = fmaf(pf, wwf,    0.00943887047f);
        pf = fmaf(pf, wwf,    1.00167406f);
        pf = fmaf(pf, wwf,    2.83297682f);
        p = lt ? pn : pf;
    }
    return p * u;
}

// =====================================================================
// Fused producer-consumer kernel, SYNC-FREE ring handoff.
//   grid = NELEM/EPB = 704 blocks x 576 threads (9 waves).
//   waves 0..7 (producers): free-run threefry+erfinv over private k-list
//     (k % 8 == wid), writing a 64-slot LDS ring; per-slot flag = k+1
//     after threadfence. Credit-blocked only if 64 ahead of consumer
//     (rare: consumer is ~10x faster than producer aggregate).
//   wave 8 (consumer): probes 64 flags in ONE lane-indexed ds_read,
//     ballot -> ready-run length, consumes run, publishes position.
// No __syncthreads in the main loop: producers never wait on each other.
// LDS: tabP 16K + tabC 8K + ring 16K + flags 0.25K ~ 40.6 KB -> 3 blk/CU.
// =====================================================================
__global__ __launch_bounds__(BLK)
void fused_kernel(const float* __restrict__ skes,
                  const float* __restrict__ silT,
                  const float* __restrict__ wskes,
                  const float* __restrict__ wsil_p,
                  const float* __restrict__ tsc_p,
                  float* __restrict__ out) {
    __shared__ __align__(16) uint4    tabP[NSTEP];   // {c1s, e, k0, k1}
    __shared__ __align__(8)  uint2    tabC[NSTEP];   // {A, temb*2log2e}
    __shared__ __align__(16) float    dbuf[RING][EPB];
    __shared__ uint32_t               flags[RING];
    __shared__ uint32_t               consPos;

    const float wsil = wsil_p[0];
    const float tsc  = tsc_p[0];
    const float L2E2 = 2.8853900817779268f;      // 2*log2(e)

    // ---- one-time schedule init: 2 rows/thread ----
    for (int k = (int)threadIdx.x; k < NSTEP; k += BLK) {
        const int t = 999 - k;
        const float at  = ALPH.a[t + 1];
        const float atn = ALPH.a[t];
        const float c1 = 0.1f * sqrtf((1.0f - at / atn) * (1.0f - atn) / (1.0f - at));
        const float c2 = sqrtf(fmaxf(1.0f - atn - c1 * c1, 0.0f));
        const float rs = 1.0f / sqrtf(1.0f - at);
        const float A  = sqrtf(atn) - c2 * sqrtf(at) * rs;
        const float e  = c2 * rs;
        const float temb = tsc * ((float)t / 1000.0f);
        // fold_in(key(42), t): key <- threefry(key=[0,42], ctr=[0,t])
        uint32_t k0 = 0u, k1 = (uint32_t)t;
        tf20(0u, 42u, 0x1BD11BDAu ^ 42u, k0, k1);
        tabP[k]  = make_uint4(__float_as_uint(c1 * 1.4142135f),
                              __float_as_uint(e), k0, k1);
        tabC[k]  = make_uint2(__float_as_uint(A), __float_as_uint(temb * L2E2));
    }
    if (threadIdx.x < RING) flags[threadIdx.x] = 0u;
    if (threadIdx.x == 0)   consPos = 0u;

    const int wid  = (int)(threadIdx.x >> 6);
    const int lane = (int)(threadIdx.x & 63);
    const int j    = (int)(blockIdx.x * EPB) + lane;

    const float sT = silT[j];

    // consumer-only per-lane state
    float cc2 = 0.0f, ws2 = 0.0f, sil = 0.0f;
    if (wid == PW) {
        const int ns = j / HW;
        const int hw = j - ns * HW;
        const int n  = ns >> 3;
        const int ss = ns & 7;
        const float* sk = skes + (size_t)((n * 3) * 8 + ss) * HW + hw;
        const float w0 = wskes[0], w1 = wskes[1], w2 = wskes[2];
        const float cond = fmaf(w2, sk[2 * 8 * HW], fmaf(w1, sk[8 * HW], w0 * sk[0]));
        cc2 = cond * L2E2;
        ws2 = wsil * L2E2;
        sil = sT;
    }

    __syncthreads();   // tables + ring init visible; the ONLY barrier.

    if (wid < PW) {
        // ================= producer wave: free-run =================
        __builtin_amdgcn_s_setprio(1);   // favor producers over consumer polls
        volatile uint32_t* vcons = &consPos;
        int cached = 0;
#pragma unroll 1
        for (int k = wid; k < NSTEP; k += PW) {
            if (k >= RING) {             // slot reuse credit (rarely blocks)
                const int need = k - RING + 1;
                while (cached < need) {
                    cached = (int)*vcons;
                    if (cached < need) __builtin_amdgcn_s_sleep(1);
                }
            }
            const uint4 ta = tabP[k];
            uint32_t x0 = 0u, x1 = (uint32_t)j;      // partitionable ctr (0, j)
            tf20(ta.z, ta.w, ta.z ^ ta.w ^ 0x1BD11BDAu, x0, x1);
            const float ei = bits_to_erfinv(x0 ^ x1);
            dbuf[k & (RING - 1)][lane] =
                fmaf(__uint_as_float(ta.x), ei, __uint_as_float(ta.y) * sT);
            __threadfence_block();       // data in LDS before flag
            if (lane == 0)
                ((volatile uint32_t*)flags)[k & (RING - 1)] = (uint32_t)(k + 1);
        }
    } else {
        // ================= consumer wave: chase the frontier =================
        volatile uint32_t* vflags = flags;
        float* op = out + j;
        int k = 0;
        while (k < NSTEP) {
            // lane l probes readiness of step k+l (one ds_read for 64 steps)
            const int kl = k + lane;
            bool ready = true;
            if (kl < NSTEP)
                ready = (vflags[kl & (RING - 1)] == (uint32_t)(kl + 1));
            const unsigned long long m = __ballot(ready);
            int run = (~m == 0ull) ? 64 : (__ffsll((unsigned long long)~m) - 1);
            if (run <= 0) { __builtin_amdgcn_s_sleep(1); continue; }
            if (run > NSTEP - k) run = NSTEP - k;
#pragma unroll 1
            for (int i = 0; i < run; ++i) {
                const float d  = dbuf[(k + i) & (RING - 1)][lane];
                const uint2 tt = tabC[k + i];
                const float A  = __uint_as_float(tt.x);
                const float tb = __uint_as_float(tt.y);
                const float e2 = __builtin_amdgcn_exp2f(fmaf(ws2, sil, cc2 + tb));
                const float r  = __builtin_amdgcn_rcpf(e2 + 1.0f);
                const float s0 = fmaf(-2.0f, r, 1.0f);
                *op = s0; op += NELEM;
                sil = fmaf(A, s0, d);
            }
            k += run;
            __threadfence_block();       // ring reads retired before credit
            if (lane == 0) *((volatile uint32_t*)&consPos) = (uint32_t)k;
        }
    }
}

extern "C" void kernel_launch(void* const* d_in, const int* in_sizes, int n_in,
                              void* d_out, int out_size, void* d_ws, size_t ws_size,
                              hipStream_t stream) {
    const float* skes = (const float*)d_in[0];
    const float* silT = (const float*)d_in[1];
    const float* wsk  = (const float*)d_in[2];
    const float* wsil = (const float*)d_in[3];
    const float* tsc  = (const float*)d_in[4];
    float* out = (float*)d_out;
    (void)in_sizes; (void)n_in; (void)out_size; (void)d_ws; (void)ws_size;

    dim3 grid(NELEM / EPB), block(BLK);
    hipLaunchKernelGGL(fused_kernel, grid, block, 0, stream,
                       skes, silT, wsk, wsil, tsc, out);
}

// Round 6
// 432.123 us; speedup vs baseline: 1.0081x; 1.0081x over previous
//
#include <hip/hip_runtime.h>
#include <cstdint>

#define NSTEP 1000
#define NELEM 45056          // 16 * 2816  (n*s = 16 slices of 64x44)
#define HW    2816           // 64 * 44
#define EPB   64             // elements per block == consumer wave width
#define PW    8              // producer waves per block
#define BLK   ((PW + 1) * 64)// 576 threads: 8 producer waves + 1 consumer wave
#define RING  64             // LDS ring slots (power of 2)

// ---------- compile-time fp64 DDIM schedule (bit-exact vs np.linspace+cumprod) ----------
struct AlphTab { float a[NSTEP + 1]; };

constexpr AlphTab make_alph() {
    AlphTab t{};
    t.a[0] = 1.0f;
    double alph = 1.0;
    const double start = 1e-4, stop = 0.02;
    const double step = (stop - start) / 999.0;
    for (int i = 0; i < NSTEP; ++i) {
        double beta = (i == NSTEP - 1) ? stop : ((double)i * step + start);
        alph *= (1.0 - beta);
        t.a[i + 1] = (float)alph;
    }
    return t;
}
constexpr AlphTab ALPH = make_alph();

// ---------- Threefry-2x32-20 (partitionable-mode usage: ctr=(0,j), out = x0^x1) ----------
__device__ __forceinline__ void tf20(uint32_t K0, uint32_t K1, uint32_t K2,
                                     uint32_t& x0, uint32_t& x1) {
    x0 += K0; x1 += K1;
#define TFR(r) { x0 += x1; x1 = ((x1 << r) | (x1 >> (32 - r))); x1 ^= x0; }
    TFR(13) TFR(15) TFR(26) TFR(6)
    x0 += K1; x1 += K2 + 1u;
    TFR(17) TFR(29) TFR(16) TFR(24)
    x0 += K2; x1 += K0 + 2u;
    TFR(13) TFR(15) TFR(26) TFR(6)
    x0 += K0; x1 += K1 + 3u;
    TFR(17) TFR(29) TFR(16) TFR(24)
    x0 += K1; x1 += K2 + 4u;
    TFR(13) TFR(15) TFR(26) TFR(6)
    x0 += K2; x1 += K0 + 5u;
#undef TFR
}

// bits -> erfinv(u). Dual-poly, single select; wave-uniform skip of the far
// branch (P(any of 64 lanes far) ~ 19%). Bit-identical to the reference poly.
__device__ __forceinline__ float bits_to_erfinv(uint32_t bits) {
    const float f2 = __uint_as_float((bits >> 9) | 0x3F800000u) - 1.0f;
    const float u  = f2 * 2.0f - 0.99999994f;
    const float t1 = (1.0f - u) * (1.0f + u);
    const float w  = __log2f(t1) * -0.6931472f;
    const bool  lt = w < 5.0f;

    const float wwn = w - 2.5f;
    float pn =           2.81022636e-08f;
    pn = fmaf(pn, wwn,   3.43273939e-07f);
    pn = fmaf(pn, wwn,  -3.5233877e-06f);
    pn = fmaf(pn, wwn,  -4.39150654e-06f);
    pn = fmaf(pn, wwn,   0.00021858087f);
    pn = fmaf(pn, wwn,  -0.00125372503f);
    pn = fmaf(pn, wwn,  -0.00417768164f);
    pn = fmaf(pn, wwn,   0.246640727f);
    pn = fmaf(pn, wwn,   1.50140941f);

    float p = pn;
    if (__any(!lt)) {                                 // wave-uniform branch
        const float sw  = __builtin_amdgcn_sqrtf(w);  // w >= 0 always
        const float wwf = sw - 3.0f;
        float pf =           -0.000200214257f;
        pf = fmaf(pf, wwf,    0.000100950558f);
        pf = fmaf(pf, wwf,    0.00134934322f);
        pf = fmaf(pf, wwf,   -0.00367342844f);
        pf = fmaf(pf, wwf,    0.00573950773f);
        pf = fmaf(pf, wwf,   -0.0076224613f);
        pf = fmaf(pf, wwf,    0.00943887047f);
        pf = fmaf(pf, wwf,    1.00167406f);
        pf = fmaf(pf, wwf,    2.83297682f);
        p = lt ? pn : pf;
    }
    return p * u;
}

// =====================================================================
// Fused producer-consumer kernel, FENCE-LIGHT sync-free ring handoff.
//   waves 0..7 (producers): free-run threefry+erfinv over k % 8 == wid,
//     writing a 64-slot LDS ring. Ordering of {data write -> flag write}
//     relies on in-order DS-pipe execution per wave (one DS pipe/CU, no
//     cache in front of LDS) + a compiler-only barrier. No waitcnt, no
//     threadfence in the hot loop (round-5's mistake).
//   flag/credit stores: all 64 lanes store the same value to the same
//     LDS address (broadcast-merge) -- 1 instr, no exec-mask juggling.
//   wave 8 (consumer): probes 64 flags in ONE lane-indexed ds_read,
//     ballot -> ready-run length, consumes run, publishes position.
// LDS: tabP 16K + tabC 8K + ring 16K + flags 0.25K ~ 40.6 KB -> 3 blk/CU.
// =====================================================================
__global__ __launch_bounds__(BLK)
void fused_kernel(const float* __restrict__ skes,
                  const float* __restrict__ silT,
                  const float* __restrict__ wskes,
                  const float* __restrict__ wsil_p,
                  const float* __restrict__ tsc_p,
                  float* __restrict__ out) {
    __shared__ __align__(16) uint4    tabP[NSTEP];   // {c1s, e, k0, k1}
    __shared__ __align__(8)  uint2    tabC[NSTEP];   // {A, temb*2log2e}
    __shared__ __align__(16) float    dbuf[RING][EPB];
    __shared__ uint32_t               flags[RING];
    __shared__ uint32_t               consPos;

    const float wsil = wsil_p[0];
    const float tsc  = tsc_p[0];
    const float L2E2 = 2.8853900817779268f;      // 2*log2(e)

    // ---- one-time schedule init: 2 rows/thread ----
    for (int k = (int)threadIdx.x; k < NSTEP; k += BLK) {
        const int t = 999 - k;
        const float at  = ALPH.a[t + 1];
        const float atn = ALPH.a[t];
        const float c1 = 0.1f * sqrtf((1.0f - at / atn) * (1.0f - atn) / (1.0f - at));
        const float c2 = sqrtf(fmaxf(1.0f - atn - c1 * c1, 0.0f));
        const float rs = 1.0f / sqrtf(1.0f - at);
        const float A  = sqrtf(atn) - c2 * sqrtf(at) * rs;
        const float e  = c2 * rs;
        const float temb = tsc * ((float)t / 1000.0f);
        // fold_in(key(42), t): key <- threefry(key=[0,42], ctr=[0,t])
        uint32_t k0 = 0u, k1 = (uint32_t)t;
        tf20(0u, 42u, 0x1BD11BDAu ^ 42u, k0, k1);
        tabP[k]  = make_uint4(__float_as_uint(c1 * 1.4142135f),
                              __float_as_uint(e), k0, k1);
        tabC[k]  = make_uint2(__float_as_uint(A), __float_as_uint(temb * L2E2));
    }
    if (threadIdx.x < RING) flags[threadIdx.x] = 0u;
    if (threadIdx.x == 0)   consPos = 0u;

    const int wid  = (int)(threadIdx.x >> 6);
    const int lane = (int)(threadIdx.x & 63);
    const int j    = (int)(blockIdx.x * EPB) + lane;

    const float sT = silT[j];

    // consumer-only per-lane state
    float cc2 = 0.0f, ws2 = 0.0f, sil = 0.0f;
    if (wid == PW) {
        const int ns = j / HW;
        const int hw = j - ns * HW;
        const int n  = ns >> 3;
        const int ss = ns & 7;
        const float* sk = skes + (size_t)((n * 3) * 8 + ss) * HW + hw;
        const float w0 = wskes[0], w1 = wskes[1], w2 = wskes[2];
        const float cond = fmaf(w2, sk[2 * 8 * HW], fmaf(w1, sk[8 * HW], w0 * sk[0]));
        cc2 = cond * L2E2;
        ws2 = wsil * L2E2;
        sil = sT;
    }

    __syncthreads();   // tables + ring init visible; the ONLY barrier.

    if (wid < PW) {
        // ================= producer wave: free-run =================
        __builtin_amdgcn_s_setprio(1);   // favor producers over consumer polls
        volatile uint32_t* vcons  = &consPos;
        volatile uint32_t* vflags = flags;
        int cached = 0;
#pragma unroll 1
        for (int k = wid; k < NSTEP; k += PW) {
            if (k >= RING) {             // slot reuse credit (rarely blocks)
                const int need = k - RING + 1;
                while (cached < need) {
                    cached = (int)*vcons;
                    if (cached < need) __builtin_amdgcn_s_sleep(1);
                }
            }
            const uint4 ta = tabP[k];
            uint32_t x0 = 0u, x1 = (uint32_t)j;      // partitionable ctr (0, j)
            tf20(ta.z, ta.w, ta.z ^ ta.w ^ 0x1BD11BDAu, x0, x1);
            const float ei = bits_to_erfinv(x0 ^ x1);
            dbuf[k & (RING - 1)][lane] =
                fmaf(__uint_as_float(ta.x), ei, __uint_as_float(ta.y) * sT);
            // data->flag ordering: in-order DS pipe + compiler barrier only.
            asm volatile("" ::: "memory");
            vflags[k & (RING - 1)] = (uint32_t)(k + 1);  // all lanes, same addr/value
            asm volatile("" ::: "memory");
        }
    } else {
        // ================= consumer wave: chase the frontier =================
        volatile uint32_t* vflags = flags;
        volatile uint32_t* vcons  = &consPos;
        float* op = out + j;
        int k = 0;
        while (k < NSTEP) {
            // lane l probes readiness of step k+l (one ds_read for 64 steps)
            const int kl = k + lane;
            bool ready = true;
            if (kl < NSTEP)
                ready = (vflags[kl & (RING - 1)] == (uint32_t)(kl + 1));
            const unsigned long long m = __ballot(ready);
            int run = (~m == 0ull) ? 64 : (__ffsll((unsigned long long)~m) - 1);
            if (run <= 0) { __builtin_amdgcn_s_sleep(1); continue; }
            if (run > NSTEP - k) run = NSTEP - k;
#pragma unroll 1
            for (int i = 0; i < run; ++i) {
                const float d  = dbuf[(k + i) & (RING - 1)][lane];
                const uint2 tt = tabC[k + i];
                const float A  = __uint_as_float(tt.x);
                const float tb = __uint_as_float(tt.y);
                const float e2 = __builtin_amdgcn_exp2f(fmaf(ws2, sil, cc2 + tb));
                const float r  = __builtin_amdgcn_rcpf(e2 + 1.0f);
                const float s0 = fmaf(-2.0f, r, 1.0f);
                *op = s0; op += NELEM;
                sil = fmaf(A, s0, d);
            }
            k += run;
            // reads of dbuf precede this credit store in the in-order DS pipe.
            asm volatile("" ::: "memory");
            *vcons = (uint32_t)k;                    // all lanes, same addr/value
            asm volatile("" ::: "memory");
        }
    }
}

extern "C" void kernel_launch(void* const* d_in, const int* in_sizes, int n_in,
                              void* d_out, int out_size, void* d_ws, size_t ws_size,
                              hipStream_t stream) {
    const float* skes = (const float*)d_in[0];
    const float* silT = (const float*)d_in[1];
    const float* wsk  = (const float*)d_in[2];
    const float* wsil = (const float*)d_in[3];
    const float* tsc  = (const float*)d_in[4];
    float* out = (float*)d_out;
    (void)in_sizes; (void)n_in; (void)out_size; (void)d_ws; (void)ws_size;

    dim3 grid(NELEM / EPB), block(BLK);
    hipLaunchKernelGGL(fused_kernel, grid, block, 0, stream,
                       skes, silT, wsk, wsil, tsc, out);
}

// Round 7
// 349.574 us; speedup vs baseline: 1.2462x; 1.2361x over previous
//
#include <hip/hip_runtime.h>
#include <cstdint>

#define NSTEP 1000
#define NELEM 45056          // 16 * 2816  (n*s = 16 slices of 64x44)
#define HW    2816           // 64 * 44
#define EPB   64             // elements per block == consumer wave width
#define PW    8              // producer waves per block
#define BLK   ((PW + 1) * 64)// 576 threads: 8 producer waves + 1 consumer wave
#define WIN   40             // k-steps per window; NSTEP % WIN == 0, WIN % PW == 0
#define SPP   (WIN / PW)     // 5 k-steps per producer wave per window
#define NWIN  (NSTEP / WIN)  // 25
#define NBUF  2              // windows in flight (double buffer)

// ---------- compile-time fp64 DDIM schedule (bit-exact vs np.linspace+cumprod) ----------
struct AlphTab { float a[NSTEP + 1]; };

constexpr AlphTab make_alph() {
    AlphTab t{};
    t.a[0] = 1.0f;
    double alph = 1.0;
    const double start = 1e-4, stop = 0.02;
    const double step = (stop - start) / 999.0;
    for (int i = 0; i < NSTEP; ++i) {
        double beta = (i == NSTEP - 1) ? stop : ((double)i * step + start);
        alph *= (1.0 - beta);
        t.a[i + 1] = (float)alph;
    }
    return t;
}
constexpr AlphTab ALPH = make_alph();

// ---------- Threefry-2x32-20 (partitionable-mode usage: ctr=(0,j), out = x0^x1) ----------
__device__ __forceinline__ void tf20(uint32_t K0, uint32_t K1, uint32_t K2,
                                     uint32_t& x0, uint32_t& x1) {
    x0 += K0; x1 += K1;
#define TFR(r) { x0 += x1; x1 = ((x1 << r) | (x1 >> (32 - r))); x1 ^= x0; }
    TFR(13) TFR(15) TFR(26) TFR(6)
    x0 += K1; x1 += K2 + 1u;
    TFR(17) TFR(29) TFR(16) TFR(24)
    x0 += K2; x1 += K0 + 2u;
    TFR(13) TFR(15) TFR(26) TFR(6)
    x0 += K0; x1 += K1 + 3u;
    TFR(17) TFR(29) TFR(16) TFR(24)
    x0 += K1; x1 += K2 + 4u;
    TFR(13) TFR(15) TFR(26) TFR(6)
    x0 += K2; x1 += K0 + 5u;
#undef TFR
}

// bits -> erfinv(u). Dual-poly, single select; wave-uniform skip of the far
// branch (P(any of 64 lanes far) ~ 19%). Bit-identical to the reference poly.
__device__ __forceinline__ float bits_to_erfinv(uint32_t bits) {
    const float f2 = __uint_as_float((bits >> 9) | 0x3F800000u) - 1.0f;
    const float u  = f2 * 2.0f - 0.99999994f;
    const float t1 = (1.0f - u) * (1.0f + u);
    const float w  = __log2f(t1) * -0.6931472f;
    const bool  lt = w < 5.0f;

    const float wwn = w - 2.5f;
    float pn =           2.81022636e-08f;
    pn = fmaf(pn, wwn,   3.43273939e-07f);
    pn = fmaf(pn, wwn,  -3.5233877e-06f);
    pn = fmaf(pn, wwn,  -4.39150654e-06f);
    pn = fmaf(pn, wwn,   0.00021858087f);
    pn = fmaf(pn, wwn,  -0.00125372503f);
    pn = fmaf(pn, wwn,  -0.00417768164f);
    pn = fmaf(pn, wwn,   0.246640727f);
    pn = fmaf(pn, wwn,   1.50140941f);

    float p = pn;
    if (__any(!lt)) {                                 // wave-uniform branch
        const float sw  = __builtin_amdgcn_sqrtf(w);  // w >= 0 always
        const float wwf = sw - 3.0f;
        float pf =           -0.000200214257f;
        pf = fmaf(pf, wwf,    0.000100950558f);
        pf = fmaf(pf, wwf,    0.00134934322f);
        pf = fmaf(pf, wwf,   -0.00367342844f);
        pf = fmaf(pf, wwf,    0.00573950773f);
        pf = fmaf(pf, wwf,   -0.0076224613f);
        pf = fmaf(pf, wwf,    0.00943887047f);
        pf = fmaf(pf, wwf,    1.00167406f);
        pf = fmaf(pf, wwf,    2.83297682f);
        p = lt ? pn : pf;
    }
    return p * u;
}

// =====================================================================
// Fused producer-consumer kernel, WINDOW-GRANULAR decoupled sync.
//   No __syncthreads in the main loop (r4's per-window rendezvous cost),
//   no per-step volatile ops (r5/r6's mistake). Per WINDOW (40 steps):
//     producer wave: 1 amortized credit poll + 5 steps + 1 ds_atomic_add
//     consumer wave: 1 flag poll (wincnt[w]==8) + 40 steps + 1 credit store
//   Ordering: per-wave in-order DS pipe + compiler-only barriers
//   (protocol validated bit-exact in r5/r6).
// LDS: tabP 16K + tabC 8K + dbuf 20K + wincnt ~44.6 KB -> 3 blocks/CU,
// 27 waves/CU. Producer waves free-run with +-1 window skew.
// =====================================================================
__global__ __launch_bounds__(BLK)
void fused_kernel(const float* __restrict__ skes,
                  const float* __restrict__ silT,
                  const float* __restrict__ wskes,
                  const float* __restrict__ wsil_p,
                  const float* __restrict__ tsc_p,
                  float* __restrict__ out) {
    __shared__ __align__(16) uint4    tabP[NSTEP];   // {c1s, e, k0, k1}
    __shared__ __align__(8)  uint2    tabC[NSTEP];   // {A, temb*2log2e}
    __shared__ __align__(16) float    dbuf[NBUF][WIN][EPB];
    __shared__ uint32_t               wincnt[NWIN];  // producer-done counters
    __shared__ uint32_t               consPos;       // windows fully consumed

    const float wsil = wsil_p[0];
    const float tsc  = tsc_p[0];
    const float L2E2 = 2.8853900817779268f;      // 2*log2(e)

    // ---- one-time schedule init: 2 rows/thread ----
    for (int k = (int)threadIdx.x; k < NSTEP; k += BLK) {
        const int t = 999 - k;
        const float at  = ALPH.a[t + 1];
        const float atn = ALPH.a[t];
        const float c1 = 0.1f * sqrtf((1.0f - at / atn) * (1.0f - atn) / (1.0f - at));
        const float c2 = sqrtf(fmaxf(1.0f - atn - c1 * c1, 0.0f));
        const float rs = 1.0f / sqrtf(1.0f - at);
        const float A  = sqrtf(atn) - c2 * sqrtf(at) * rs;
        const float e  = c2 * rs;
        const float temb = tsc * ((float)t / 1000.0f);
        // fold_in(key(42), t): key <- threefry(key=[0,42], ctr=[0,t])
        uint32_t k0 = 0u, k1 = (uint32_t)t;
        tf20(0u, 42u, 0x1BD11BDAu ^ 42u, k0, k1);
        tabP[k]  = make_uint4(__float_as_uint(c1 * 1.4142135f),
                              __float_as_uint(e), k0, k1);
        tabC[k]  = make_uint2(__float_as_uint(A), __float_as_uint(temb * L2E2));
    }
    if (threadIdx.x < NWIN) wincnt[threadIdx.x] = 0u;
    if (threadIdx.x == 0)   consPos = 0u;

    const int wid  = (int)(threadIdx.x >> 6);
    const int lane = (int)(threadIdx.x & 63);
    const int j    = (int)(blockIdx.x * EPB) + lane;

    const float sT = silT[j];

    // consumer-only per-lane state
    float cc2 = 0.0f, ws2 = 0.0f, sil = 0.0f;
    if (wid == PW) {
        const int ns = j / HW;
        const int hw = j - ns * HW;
        const int n  = ns >> 3;
        const int ss = ns & 7;
        const float* sk = skes + (size_t)((n * 3) * 8 + ss) * HW + hw;
        const float w0 = wskes[0], w1 = wskes[1], w2 = wskes[2];
        const float cond = fmaf(w2, sk[2 * 8 * HW], fmaf(w1, sk[8 * HW], w0 * sk[0]));
        cc2 = cond * L2E2;
        ws2 = wsil * L2E2;
        sil = sT;
    }

    __syncthreads();   // tables + counters visible; the ONLY barrier.

    if (wid < PW) {
        // ================= producer wave: window free-run =================
        __builtin_amdgcn_s_setprio(1);
        volatile uint32_t* vcons = &consPos;
#pragma unroll 1
        for (int w = 0; w < NWIN; ++w) {
            if (w >= NBUF) {             // amortized credit poll (1 per 5 steps)
                const uint32_t need = (uint32_t)(w - NBUF + 1);
                while (*vcons < need) __builtin_amdgcn_s_sleep(2);
            }
            const int kbase = w * WIN + wid;
            // hoist the window's 5 table reads into registers (batched ds_reads)
            uint4 tt[SPP];
#pragma unroll
            for (int s = 0; s < SPP; ++s) tt[s] = tabP[kbase + s * PW];
            float* db = &dbuf[w & (NBUF - 1)][0][0];
#pragma unroll
            for (int s = 0; s < SPP; ++s) {
                uint32_t x0 = 0u, x1 = (uint32_t)j;  // partitionable ctr (0, j)
                tf20(tt[s].z, tt[s].w, tt[s].z ^ tt[s].w ^ 0x1BD11BDAu, x0, x1);
                const float ei = bits_to_erfinv(x0 ^ x1);
                db[(wid + s * PW) * EPB + lane] =
                    fmaf(__uint_as_float(tt[s].x), ei,
                         __uint_as_float(tt[s].y) * sT);
            }
            // data writes precede the counter bump in this wave's in-order DS pipe
            asm volatile("" ::: "memory");
            if (lane == 0) atomicAdd(&wincnt[w], 1u);
            asm volatile("" ::: "memory");
        }
    } else {
        // ================= consumer wave: window chase =================
        volatile uint32_t* vwin  = wincnt;
        volatile uint32_t* vcons = &consPos;
        float* op = out + j;
#pragma unroll 1
        for (int w = 0; w < NWIN; ++w) {
            while (vwin[w] < (uint32_t)PW) __builtin_amdgcn_s_sleep(1);
            asm volatile("" ::: "memory");   // no dbuf read hoisted above poll
            const float* db = &dbuf[w & (NBUF - 1)][0][0];
            const int kbase = w * WIN;
#pragma unroll 1
            for (int g = 0; g < WIN / 4; ++g) {
                // batch the 4 noise + 4 schedule reads, then run the chain
                float d4[4]; uint2 t4[4];
#pragma unroll
                for (int i = 0; i < 4; ++i) {
                    d4[i] = db[(g * 4 + i) * EPB + lane];
                    t4[i] = tabC[kbase + g * 4 + i];
                }
#pragma unroll
                for (int i = 0; i < 4; ++i) {
                    const float A  = __uint_as_float(t4[i].x);
                    const float tb = __uint_as_float(t4[i].y);
                    const float e2 = __builtin_amdgcn_exp2f(fmaf(ws2, sil, cc2 + tb));
                    const float r  = __builtin_amdgcn_rcpf(e2 + 1.0f);
                    const float s0 = fmaf(-2.0f, r, 1.0f);
                    *op = s0; op += NELEM;
                    sil = fmaf(A, s0, d4[i]);
                }
            }
            // dbuf reads precede the credit store in this wave's in-order DS pipe
            asm volatile("" ::: "memory");
            *vcons = (uint32_t)(w + 1);      // all lanes, same addr/value
            asm volatile("" ::: "memory");
        }
    }
}

extern "C" void kernel_launch(void* const* d_in, const int* in_sizes, int n_in,
                              void* d_out, int out_size, void* d_ws, size_t ws_size,
                              hipStream_t stream) {
    const float* skes = (const float*)d_in[0];
    const float* silT = (const float*)d_in[1];
    const float* wsk  = (const float*)d_in[2];
    const float* wsil = (const float*)d_in[3];
    const float* tsc  = (const float*)d_in[4];
    float* out = (float*)d_out;
    (void)in_sizes; (void)n_in; (void)out_size; (void)d_ws; (void)ws_size;

    dim3 grid(NELEM / EPB), block(BLK);
    hipLaunchKernelGGL(fused_kernel, grid, block, 0, stream,
                       skes, silT, wsk, wsil, tsc, out);
}

// Round 8
// 294.204 us; speedup vs baseline: 1.4807x; 1.1882x over previous
//
#include <hip/hip_runtime.h>
#include <cstdint>

#define NSTEP 1000
#define NELEM 45056          // 16 * 2816  (n*s = 16 slices of 64x44)
#define HW    2816           // 64 * 44
#define EPB   64             // elements per block == consumer wave width
#define PW    7              // producer waves per block
#define BLK   ((PW + 1) * 64)// 512 threads: 7 producer waves + 1 consumer wave
#define WIN   40             // k-steps per window; NSTEP % WIN == 0
#define NWIN  (NSTEP / WIN)  // 25
#define NBUF  2              // windows in flight (double buffer)
#define TABC_OFF 16384       // byte offset of tabC in workspace
#define WS_NEED  (TABC_OFF + NSTEP * 8)

// ---------- compile-time fp64 DDIM schedule (bit-exact vs np.linspace+cumprod) ----------
struct AlphTab { float a[NSTEP + 1]; };

constexpr AlphTab make_alph() {
    AlphTab t{};
    t.a[0] = 1.0f;
    double alph = 1.0;
    const double start = 1e-4, stop = 0.02;
    const double step = (stop - start) / 999.0;
    for (int i = 0; i < NSTEP; ++i) {
        double beta = (i == NSTEP - 1) ? stop : ((double)i * step + start);
        alph *= (1.0 - beta);
        t.a[i + 1] = (float)alph;
    }
    return t;
}
constexpr AlphTab ALPH = make_alph();

// ---------- Threefry-2x32-20 (partitionable-mode usage: ctr=(0,j), out = x0^x1) ----------
__device__ __forceinline__ void tf20(uint32_t K0, uint32_t K1, uint32_t K2,
                                     uint32_t& x0, uint32_t& x1) {
    x0 += K0; x1 += K1;
#define TFR(r) { x0 += x1; x1 = ((x1 << r) | (x1 >> (32 - r))); x1 ^= x0; }
    TFR(13) TFR(15) TFR(26) TFR(6)
    x0 += K1; x1 += K2 + 1u;
    TFR(17) TFR(29) TFR(16) TFR(24)
    x0 += K2; x1 += K0 + 2u;
    TFR(13) TFR(15) TFR(26) TFR(6)
    x0 += K0; x1 += K1 + 3u;
    TFR(17) TFR(29) TFR(16) TFR(24)
    x0 += K1; x1 += K2 + 4u;
    TFR(13) TFR(15) TFR(26) TFR(6)
    x0 += K2; x1 += K0 + 5u;
#undef TFR
}

__device__ __forceinline__ float fast_tanh(float x) {
    const float e2 = __expf(x + x);
    const float r  = __builtin_amdgcn_rcpf(e2 + 1.0f);
    return fmaf(-2.0f, r, 1.0f);
}

// bits -> erfinv(u). Dual-poly, single select; wave-uniform skip of the far
// branch (P(any of 64 lanes far) ~ 19%). Bit-identical to the reference poly.
__device__ __forceinline__ float bits_to_erfinv(uint32_t bits) {
    const float f2 = __uint_as_float((bits >> 9) | 0x3F800000u) - 1.0f;
    const float u  = f2 * 2.0f - 0.99999994f;
    const float t1 = (1.0f - u) * (1.0f + u);
    const float w  = __log2f(t1) * -0.6931472f;
    const bool  lt = w < 5.0f;

    const float wwn = w - 2.5f;
    float pn =           2.81022636e-08f;
    pn = fmaf(pn, wwn,   3.43273939e-07f);
    pn = fmaf(pn, wwn,  -3.5233877e-06f);
    pn = fmaf(pn, wwn,  -4.39150654e-06f);
    pn = fmaf(pn, wwn,   0.00021858087f);
    pn = fmaf(pn, wwn,  -0.00125372503f);
    pn = fmaf(pn, wwn,  -0.00417768164f);
    pn = fmaf(pn, wwn,   0.246640727f);
    pn = fmaf(pn, wwn,   1.50140941f);

    float p = pn;
    if (__any(!lt)) {                                 // wave-uniform branch
        const float sw  = __builtin_amdgcn_sqrtf(w);  // w >= 0 always
        const float wwf = sw - 3.0f;
        float pf =           -0.000200214257f;
        pf = fmaf(pf, wwf,    0.000100950558f);
        pf = fmaf(pf, wwf,    0.00134934322f);
        pf = fmaf(pf, wwf,   -0.00367342844f);
        pf = fmaf(pf, wwf,    0.00573950773f);
        pf = fmaf(pf, wwf,   -0.0076224613f);
        pf = fmaf(pf, wwf,    0.00943887047f);
        pf = fmaf(pf, wwf,    1.00167406f);
        pf = fmaf(pf, wwf,    2.83297682f);
        p = lt ? pn : pf;
    }
    return p * u;
}

// =====================================================================
// Setup kernel: DDIM schedule + per-step threefry keys -> GLOBAL memory.
// Runs once (4 blocks x 256). Tables are wave-uniform in the main kernel,
// so they are read there via scalar loads (SMEM pipe) -- zero DS traffic.
// =====================================================================
__global__ __launch_bounds__(256)
void setup_kernel(const float* __restrict__ tsc_p,
                  uint4* __restrict__ tabPg, uint2* __restrict__ tabCg) {
    const int k = (int)(blockIdx.x * 256u + threadIdx.x);
    if (k >= NSTEP) return;
    const float tsc = tsc_p[0];
    const float L2E2 = 2.8853900817779268f;      // 2*log2(e)
    const int t = 999 - k;
    const float at  = ALPH.a[t + 1];
    const float atn = ALPH.a[t];
    const float c1 = 0.1f * sqrtf((1.0f - at / atn) * (1.0f - atn) / (1.0f - at));
    const float c2 = sqrtf(fmaxf(1.0f - atn - c1 * c1, 0.0f));
    const float rs = 1.0f / sqrtf(1.0f - at);
    const float A  = sqrtf(atn) - c2 * sqrtf(at) * rs;
    const float e  = c2 * rs;
    const float temb = tsc * ((float)t / 1000.0f);
    // fold_in(key(42), t): key <- threefry(key=[0,42], ctr=[0,t])
    uint32_t k0 = 0u, k1 = (uint32_t)t;
    tf20(0u, 42u, 0x1BD11BDAu ^ 42u, k0, k1);
    tabPg[k] = make_uint4(__float_as_uint(c1 * 1.4142135f),
                          __float_as_uint(e), k0, k1);
    tabCg[k] = make_uint2(__float_as_uint(A), __float_as_uint(temb * L2E2));
}

// one producer wave's share of a window. Table index is wave-uniform
// (readfirstlane) -> s_load_dwordx4; keys land in SGPRs, k2 = s_xor (SALU).
__device__ __forceinline__ void produce_window(const uint4* __restrict__ tabPg,
                                               float* __restrict__ db,
                                               int kbase, int wid, int lane,
                                               int j, float sT) {
    const int ks0 = __builtin_amdgcn_readfirstlane(kbase + wid);
#pragma unroll 2
    for (int s = 0, kk = wid; kk < WIN; ++s, kk += PW) {
        const uint4 ta = tabPg[ks0 + s * PW];
        uint32_t x0 = 0u, x1 = (uint32_t)j;      // partitionable ctr (0, j)
        tf20(ta.z, ta.w, ta.z ^ ta.w ^ 0x1BD11BDAu, x0, x1);
        const float ei = bits_to_erfinv(x0 ^ x1);
        db[kk * EPB + lane] =
            fmaf(__uint_as_float(ta.x), ei, __uint_as_float(ta.y) * sT);
    }
}

// =====================================================================
// Fused producer-consumer kernel, r4 barrier structure (best measured),
// tables in global memory via scalar loads.
//   grid = NELEM/EPB = 704 blocks x 512 threads (8 waves).
//   waves 0..6 (producers): threefry+erfinv, window w+1.
//   wave 7 (consumer): serial DDIM scan, window w, LDS -> out.
// LDS: dbuf only, 20.5 KB -> 4 blocks/CU = 32 waves/CU (hardware cap),
// exactly 8 waves/SIMD. DS pipe carries ONLY the 40 data writes +
// 40 data reads per block-window (tab traffic moved to SMEM/K$).
// =====================================================================
__global__ __launch_bounds__(BLK, 8)
void fused_kernel(const float* __restrict__ skes,
                  const float* __restrict__ silT,
                  const float* __restrict__ wskes,
                  const float* __restrict__ wsil_p,
                  const uint4* __restrict__ tabPg,
                  const uint2* __restrict__ tabCg,
                  float* __restrict__ out) {
    __shared__ __align__(16) float dbuf[NBUF][WIN][EPB];

    const int wid  = (int)(threadIdx.x >> 6);
    const int lane = (int)(threadIdx.x & 63);
    const int j    = (int)(blockIdx.x * EPB) + lane;

    const float sT = silT[j];

    // consumer-only per-lane state
    float cc2 = 0.0f, ws2 = 0.0f, sil = 0.0f;
    if (wid == PW) {
        const float L2E2 = 2.8853900817779268f;
        const int ns = j / HW;
        const int hw = j - ns * HW;
        const int n  = ns >> 3;
        const int ss = ns & 7;
        const float* sk = skes + (size_t)((n * 3) * 8 + ss) * HW + hw;
        const float w0 = wskes[0], w1 = wskes[1], w2 = wskes[2];
        const float cond = fmaf(w2, sk[2 * 8 * HW], fmaf(w1, sk[8 * HW], w0 * sk[0]));
        cc2 = cond * L2E2;
        ws2 = wsil_p[0] * L2E2;
        sil = sT;
    }

    // ---- prologue: producers fill window 0 ----
    if (wid < PW) {
        produce_window(tabPg, &dbuf[0][0][0], 0, wid, lane, j, sT);
    }
    __syncthreads();   // window 0 ready

    float* op = out + j;

    for (int w = 0; w < NWIN; ++w) {
        if (wid < PW) {
            // ---- producers: fill window w+1 into the other buffer ----
            if (w + 1 < NWIN) {
                produce_window(tabPg, &dbuf[(w + 1) & (NBUF - 1)][0][0],
                               (w + 1) * WIN, wid, lane, j, sT);
            }
        } else {
            // ---- consumer: serial scan over window w ----
            const float* db = &dbuf[w & (NBUF - 1)][0][0];
            const int ks0 = __builtin_amdgcn_readfirstlane(w * WIN);
#pragma unroll 1
            for (int g = 0; g < WIN / 8; ++g) {
                // batch 8 noise (DS b32, conflict-free) + 8 schedule (s_load) reads
                float d8[8]; uint2 t8[8];
#pragma unroll
                for (int i = 0; i < 8; ++i) {
                    d8[i] = db[(g * 8 + i) * EPB + lane];
                    t8[i] = tabCg[ks0 + g * 8 + i];
                }
#pragma unroll
                for (int i = 0; i < 8; ++i) {
                    const float A  = __uint_as_float(t8[i].x);
                    const float tb = __uint_as_float(t8[i].y);
                    const float e2 = __builtin_amdgcn_exp2f(fmaf(ws2, sil, cc2 + tb));
                    const float r  = __builtin_amdgcn_rcpf(e2 + 1.0f);
                    const float s0 = fmaf(-2.0f, r, 1.0f);
                    *op = s0; op += NELEM;
                    sil = fmaf(A, s0, d8[i]);
                }
            }
        }
        __syncthreads();   // window w consumed / window w+1 ready
    }
}

// =====================================================================
// Fallback: monolithic kernel (only if ws_size too small). r0 semantics.
// =====================================================================
__global__ __launch_bounds__(256)
void diffgait_mono(const float* __restrict__ skes,
                   const float* __restrict__ silT,
                   const float* __restrict__ wskes,
                   const float* __restrict__ wsil_p,
                   const float* __restrict__ tsc_p,
                   float* __restrict__ out) {
    __shared__ __align__(16) uint32_t tab[NSTEP][8];
    const float wsil = wsil_p[0];
    const float tsc  = tsc_p[0];
    for (int k = (int)threadIdx.x; k < NSTEP; k += 256) {
        const int t = 999 - k;
        const float at  = ALPH.a[t + 1];
        const float atn = ALPH.a[t];
        const float c1 = 0.1f * sqrtf((1.0f - at / atn) * (1.0f - atn) / (1.0f - at));
        const float c2 = sqrtf(fmaxf(1.0f - atn - c1 * c1, 0.0f));
        const float rs = 1.0f / sqrtf(1.0f - at);
        const float A  = sqrtf(atn) - c2 * sqrtf(at) * rs;
        const float e  = c2 * rs;
        const float temb = tsc * ((float)t / 1000.0f);
        uint32_t x0 = 0u, x1 = (uint32_t)t;
        tf20(0u, 42u, 0x1BD11BDAu ^ 42u, x0, x1);
        tab[k][0] = __float_as_uint(A);
        tab[k][1] = __float_as_uint(temb);
        tab[k][2] = __float_as_uint(c1 * 1.4142135f);
        tab[k][3] = __float_as_uint(e);
        tab[k][4] = x0;
        tab[k][5] = x1;
        tab[k][6] = x0 ^ x1 ^ 0x1BD11BDAu;
        tab[k][7] = 0u;
    }
    __syncthreads();
    const int j  = (int)(blockIdx.x * 256u + threadIdx.x);
    const int ns = j / HW;
    const int hw = j - ns * HW;
    const int n  = ns >> 3;
    const int ss = ns & 7;
    const float* sk = skes + (size_t)((n * 3) * 8 + ss) * HW + hw;
    const float w0 = wskes[0], w1 = wskes[1], w2 = wskes[2];
    const float cond = fmaf(w2, sk[2 * 8 * HW], fmaf(w1, sk[8 * HW], w0 * sk[0]));
    const float sT = silT[j];
    float sil = sT;
    float* op = out + j;
#pragma unroll 2
    for (int k = 0; k < NSTEP; ++k) {
        const uint4 ta = *(const uint4*)&tab[k][0];
        const uint4 tb = *(const uint4*)&tab[k][4];
        uint32_t x0 = 0u, x1 = (uint32_t)j;
        tf20(tb.x, tb.y, tb.z, x0, x1);
        const float ei = bits_to_erfinv(x0 ^ x1);
        const float d  = fmaf(__uint_as_float(ta.z), ei, __uint_as_float(ta.w) * sT);
        const float s0 = fast_tanh(fmaf(wsil, sil, cond) + __uint_as_float(ta.y));
        *op = s0; op += NELEM;
        sil = fmaf(__uint_as_float(ta.x), s0, d);
    }
}

extern "C" void kernel_launch(void* const* d_in, const int* in_sizes, int n_in,
                              void* d_out, int out_size, void* d_ws, size_t ws_size,
                              hipStream_t stream) {
    const float* skes = (const float*)d_in[0];
    const float* silT = (const float*)d_in[1];
    const float* wsk  = (const float*)d_in[2];
    const float* wsil = (const float*)d_in[3];
    const float* tsc  = (const float*)d_in[4];
    float* out = (float*)d_out;
    (void)in_sizes; (void)n_in; (void)out_size;

    if (ws_size >= (size_t)WS_NEED) {
        uint4* tabPg = (uint4*)d_ws;
        uint2* tabCg = (uint2*)((char*)d_ws + TABC_OFF);
        hipLaunchKernelGGL(setup_kernel, dim3(4), dim3(256), 0, stream,
                           tsc, tabPg, tabCg);
        dim3 grid(NELEM / EPB), block(BLK);
        hipLaunchKernelGGL(fused_kernel, grid, block, 0, stream,
                           skes, silT, wsk, wsil, tabPg, tabCg, out);
    } else {
        dim3 grid(NELEM / 256), block(256);
        hipLaunchKernelGGL(diffgait_mono, grid, block, 0, stream,
                           skes, silT, wsk, wsil, tsc, out);
    }
}